// Round 13
// 336.150 us; speedup vs baseline: 2.5638x; 1.1135x over previous
//
#include <hip/hip_runtime.h>
#include <cmath>

#define NN   3072
#define HIDD 256
#define TK   16
#define FEAT 768   // 3*HID

typedef __attribute__((ext_vector_type(8))) short bf16x8;
typedef __attribute__((ext_vector_type(4))) float f32x4;

__device__ inline unsigned short f2bf(float x) {
    unsigned u = __float_as_uint(x);
    unsigned r = (u + 0x7FFFu + ((u >> 16) & 1u)) >> 16;   // RNE
    return (unsigned short)r;
}
__device__ inline float bf2f(unsigned short h) {
    return __uint_as_float(((unsigned)h) << 16);
}

// ---------------------------------------------------------------- pool (+ all zero-init)
__global__ void pool_kernel(const float* __restrict__ img, float* __restrict__ p,
                            float* __restrict__ Dv, float* __restrict__ Dv2,
                            int* __restrict__ row_cnt, int* __restrict__ row_fill,
                            float* __restrict__ csum, float* __restrict__ numb,
                            float* __restrict__ msum) {
    int idx = blockIdx.x * 256 + threadIdx.x;
    if (idx < NN) { Dv[idx] = 0.f; Dv2[idx] = 0.f; row_cnt[idx] = 0; row_fill[idx] = 0; }
    if (idx < 2 * FEAT) csum[idx] = 0.f;     // csum | csum2 contiguous
    if (idx < 128) numb[idx] = 0.f;          // numb | denb contiguous
    if (idx == 0) msum[0] = 0.f;
    if (idx >= NN * 192) return;
    int b = idx / 192, rem = idx % 192;
    int c = rem >> 6, oy = (rem >> 3) & 7, ox = rem & 7;
    const float* base = img + (((size_t)b * 3 + c) * 32 + oy * 4) * 32 + ox * 4;
    float s = 0.f;
#pragma unroll
    for (int iy = 0; iy < 4; iy++)
#pragma unroll
        for (int ix = 0; ix < 4; ix++) s += base[iy * 32 + ix];
    p[idx] = s * 0.0625f;
}

// ---------------------------------------------------------------- batched input -> bf16 (3 jobs)
__global__ void split_rows3(const float* __restrict__ X0, short* __restrict__ C0,
                            const float* __restrict__ X1, short* __restrict__ C1,
                            const float* __restrict__ X2, short* __restrict__ C2) {
    int i = blockIdx.x * 256 + threadIdx.x;
    const float* X; short* Xc; int K;
    if (i < NN * 48) { X = X0; Xc = C0; K = 192; }
    else if (i < NN * 240) { X = X1; Xc = C1; K = 768; i -= NN * 48; }
    else if (i < NN * 304) { X = X2; Xc = C2; K = 256; i -= NN * 240; }
    else return;
    int K4 = K >> 2;
    int m = i / K4, f = i - m * K4;
    float4 v = *(const float4*)(X + (size_t)m * K + f * 4);
    *(short4*)(Xc + (size_t)m * K + f * 4) =
        make_short4((short)f2bf(v.x), (short)f2bf(v.y), (short)f2bf(v.z), (short)f2bf(v.w));
}

// ---------------------------------------------------------------- batched weight transpose -> bf16
struct WJ { const float* W; short* Wc; int K; int N; };
struct WJobs { WJ j[14]; };

__global__ void wsplitT(WJobs js) {
    WJ jb = js.j[blockIdx.z];
    int tk = blockIdx.x * 32, tn = blockIdx.y * 32;
    if (tk >= jb.K || tn >= jb.N) return;
    __shared__ float t[32][33];
    int kk = threadIdx.x >> 3, nn = (threadIdx.x & 7) * 4;
    float4 v = *(const float4*)(jb.W + (size_t)(tk + kk) * jb.N + tn + nn);
    t[kk][nn + 0] = v.x; t[kk][nn + 1] = v.y; t[kk][nn + 2] = v.z; t[kk][nn + 3] = v.w;
    __syncthreads();
    int n2 = threadIdx.x >> 3, k2 = (threadIdx.x & 7) * 4;
    float a = t[k2 + 0][n2], b = t[k2 + 1][n2], c = t[k2 + 2][n2], d = t[k2 + 3][n2];
    *(short4*)(jb.Wc + (size_t)(tn + n2) * jb.K + tk + k2) =
        make_short4((short)f2bf(a), (short)f2bf(b), (short)f2bf(c), (short)f2bf(d));
}

// ---------------------------------------------------------------- job-based bf16 NT GEMM
struct BJ {
    const short* A;      // [M][sa] bf16
    const short* Bw;     // [N][sb] bf16
    const float* bias;
    float* Cf;
    short* Cc;           // bf16 out, row stride ccW
    const float* mseRef; // if set: accumulate (x-ref)^2 into msum
    int sa, sb, Koff, Klen;
    int act;             // 0 none, 1 relu, 2 tanh
    int ldc, ccW;
    int pslot;           // >=0: raw partial to P + pslot*M*Nc
    float scale;
};
struct BTJ { BJ j[6]; };

__global__ __launch_bounds__(256) void gemm_btj(BTJ bt, float* __restrict__ P,
        float* __restrict__ msum, int M, int Nc) {
    __shared__ short As[128 * 64];
    __shared__ short Bs[64 * 64];
    BJ j = bt.j[blockIdx.z];
    int tid = threadIdx.x, wave = tid >> 6, lane = tid & 63;
    int wm = (wave >> 1) * 64, wn = (wave & 1) * 32;
    int lrow = lane & 15, lk = lane >> 4;
    int m0 = blockIdx.y * 128, n0 = blockIdx.x * 64;
    int kend = j.Koff + j.Klen;
    f32x4 acc[4][2] = {};

    for (int k0 = j.Koff; k0 < kend; k0 += 64) {
#pragma unroll
        for (int i = 0; i < 4; i++) {
            int q = tid + i * 256;
            int row = q >> 3, c = q & 7;
            int dst = row * 128 + ((c ^ (row & 7)) << 4);
            *(float4*)((char*)As + dst) =
                *(const float4*)((const char*)j.A + (((size_t)(m0 + row) * j.sa + k0) << 1) + (c << 4));
        }
#pragma unroll
        for (int i = 0; i < 2; i++) {
            int q = tid + i * 256;
            int row = q >> 3, c = q & 7;
            int dst = row * 128 + ((c ^ (row & 7)) << 4);
            *(float4*)((char*)Bs + dst) =
                *(const float4*)((const char*)j.Bw + (((size_t)(n0 + row) * j.sb + k0) << 1) + (c << 4));
        }
        __syncthreads();
#pragma unroll
        for (int kk = 0; kk < 2; kk++) {
            int ck = kk * 4 + lk;
            bf16x8 af[4], bg[2];
#pragma unroll
            for (int t = 0; t < 4; t++) {
                int ra = wm + t * 16 + lrow;
                af[t] = *(const bf16x8*)((const char*)As + ra * 128 + ((ck ^ (ra & 7)) << 4));
            }
#pragma unroll
            for (int u = 0; u < 2; u++) {
                int rb = wn + u * 16 + lrow;
                bg[u] = *(const bf16x8*)((const char*)Bs + rb * 128 + ((ck ^ (rb & 7)) << 4));
            }
#pragma unroll
            for (int i2 = 0; i2 < 4; i2++)
#pragma unroll
                for (int j2 = 0; j2 < 2; j2++)
                    acc[i2][j2] = __builtin_amdgcn_mfma_f32_16x16x32_bf16(af[i2], bg[j2], acc[i2][j2], 0, 0, 0);
        }
        __syncthreads();
    }

    if (j.pslot >= 0) {
        float* Pp = P + (size_t)j.pslot * M * Nc;
#pragma unroll
        for (int i2 = 0; i2 < 4; i2++) {
            int gmb = m0 + wm + i2 * 16 + lk * 4;
#pragma unroll
            for (int j2 = 0; j2 < 2; j2++) {
                int gn = n0 + wn + j2 * 16 + lrow;
#pragma unroll
                for (int rg = 0; rg < 4; rg++)
                    Pp[(size_t)(gmb + rg) * Nc + gn] = j.scale * acc[i2][j2][rg];
            }
        }
    } else if (j.mseRef) {
        float lsum = 0.f;
#pragma unroll
        for (int i2 = 0; i2 < 4; i2++) {
            int gmb = m0 + wm + i2 * 16 + lk * 4;
#pragma unroll
            for (int j2 = 0; j2 < 2; j2++) {
                int gn = n0 + wn + j2 * 16 + lrow;
#pragma unroll
                for (int rg = 0; rg < 4; rg++) {
                    float x = acc[i2][j2][rg] + j.bias[gn];
                    float d = x - j.mseRef[(size_t)(gmb + rg) * Nc + gn];
                    lsum += d * d;
                }
            }
        }
        float* rs = (float*)As;
        rs[tid] = lsum;
        __syncthreads();
        for (int st = 128; st > 0; st >>= 1) {
            if (tid < st) rs[tid] += rs[tid + st];
            __syncthreads();
        }
        if (tid == 0) atomicAdd(msum, rs[0]);
    } else {
#pragma unroll
        for (int i2 = 0; i2 < 4; i2++) {
            int gmb = m0 + wm + i2 * 16 + lk * 4;
#pragma unroll
            for (int j2 = 0; j2 < 2; j2++) {
                int gn = n0 + wn + j2 * 16 + lrow;
#pragma unroll
                for (int rg = 0; rg < 4; rg++) {
                    int gm = gmb + rg;
                    float x = acc[i2][j2][rg];
                    if (j.bias) x += j.bias[gn];
                    if (j.act == 1) x = fmaxf(x, 0.f);
                    else if (j.act == 2) x = tanhf(x);
                    if (j.Cf) j.Cf[(size_t)gm * j.ldc + gn] = x;
                    if (j.Cc) j.Cc[(size_t)gm * j.ccW + gn] = (short)f2bf(x);
                }
            }
        }
    }
}

// 3-partial epilogue: relu(P0+P1+P2+bias) -> bf16
__global__ void epi3(const float* __restrict__ P, const float* __restrict__ bias,
                     short* __restrict__ Cc, int M, int Nc, int ccW) {
    int idx = blockIdx.x * 256 + threadIdx.x;
    if (idx >= M * Nc) return;
    int m = idx / Nc, n = idx - m * Nc;
    float v = P[idx] + P[(size_t)M * Nc + idx] + P[(size_t)2 * M * Nc + idx] + bias[n];
    v = fmaxf(v, 0.f);
    Cc[(size_t)m * ccW + n] = (short)f2bf(v);
}

// ---------------------------------------------------------------- bf16 GEMM fp32-in, fused relu+bf16 out (dw1)
__global__ __launch_bounds__(256) void gemm_mf(
        const float* __restrict__ A, const float* __restrict__ B,
        const float* __restrict__ bias, short* __restrict__ Cc,
        int M, int Nc, int K, int lda, int ldb, int ccW) {
    __shared__ short Ah[128 * 40];
    __shared__ short Bh[64 * 40];
    int tid = threadIdx.x, wave = tid >> 6, lane = tid & 63;
    int wm = (wave >> 1) * 64, wn = (wave & 1) * 32;
    int lrow = lane & 15, lk = lane >> 4;
    int m0 = blockIdx.y * 128, n0 = blockIdx.x * 64;
    f32x4 acc[4][2] = {};

    for (int k0 = 0; k0 < K; k0 += 32) {
#pragma unroll
        for (int i = 0; i < 4; i++) {
            int q = tid + i * 256;
            int rowm = q >> 3, kq = q & 7;
            float4 vv = *(const float4*)(A + (size_t)(m0 + rowm) * lda + k0 + kq * 4);
            *(short4*)&Ah[rowm * 40 + kq * 4] =
                make_short4((short)f2bf(vv.x), (short)f2bf(vv.y), (short)f2bf(vv.z), (short)f2bf(vv.w));
        }
#pragma unroll
        for (int i = 0; i < 2; i++) {
            int q = tid + i * 256;
            int kk2 = q >> 4, nq = q & 15;
            float4 vv = *(const float4*)(B + (size_t)(k0 + kk2) * ldb + n0 + nq * 4);
            Bh[(nq * 4 + 0) * 40 + kk2] = (short)f2bf(vv.x);
            Bh[(nq * 4 + 1) * 40 + kk2] = (short)f2bf(vv.y);
            Bh[(nq * 4 + 2) * 40 + kk2] = (short)f2bf(vv.z);
            Bh[(nq * 4 + 3) * 40 + kk2] = (short)f2bf(vv.w);
        }
        __syncthreads();
        bf16x8 ah[4], bh[2];
#pragma unroll
        for (int t2 = 0; t2 < 4; t2++)
            ah[t2] = *(const bf16x8*)&Ah[(wm + t2 * 16 + lrow) * 40 + lk * 8];
#pragma unroll
        for (int u = 0; u < 2; u++)
            bh[u] = *(const bf16x8*)&Bh[(wn + u * 16 + lrow) * 40 + lk * 8];
#pragma unroll
        for (int i2 = 0; i2 < 4; i2++)
#pragma unroll
            for (int j2 = 0; j2 < 2; j2++)
                acc[i2][j2] = __builtin_amdgcn_mfma_f32_16x16x32_bf16(ah[i2], bh[j2], acc[i2][j2], 0, 0, 0);
        __syncthreads();
    }
#pragma unroll
    for (int i2 = 0; i2 < 4; i2++) {
        int gmb = m0 + wm + i2 * 16 + lk * 4;
#pragma unroll
        for (int j2 = 0; j2 < 2; j2++) {
            int gn = n0 + wn + j2 * 16 + lrow;
#pragma unroll
            for (int rg = 0; rg < 4; rg++) {
                float x = fmaxf(acc[i2][j2][rg] + bias[gn], 0.f);
                Cc[(size_t)(gmb + rg) * ccW + gn] = (short)f2bf(x);
            }
        }
    }
}

// ---------------------------------------------------------------- sim = Zc @ Zc^T (bf16, K=256)
__global__ __launch_bounds__(256) void sim_mfma(const short* __restrict__ Zc,
                                                float* __restrict__ S) {
    __shared__ short As[128 * 64];
    __shared__ short Bs[128 * 64];
    int tid = threadIdx.x;
    int wave = tid >> 6, lane = tid & 63;
    int wm = (wave >> 1) * 64, wn = (wave & 1) * 64;
    int m0 = blockIdx.y * 128, n0 = blockIdx.x * 128;
    int lrow = lane & 15, lk = lane >> 4;
    f32x4 acc[4][4] = {};

    for (int k0 = 0; k0 < 256; k0 += 64) {
#pragma unroll
        for (int i = 0; i < 4; i++) {
            int q = tid + i * 256;
            int row = q >> 3, c = q & 7;
            int dstoff = row * 128 + ((c ^ (row & 7)) << 4);
            const char* pa = (const char*)Zc + (((size_t)(m0 + row) * 256 + k0) << 1) + (c << 4);
            *(float4*)((char*)As + dstoff) = *(const float4*)pa;
            const char* pb = (const char*)Zc + (((size_t)(n0 + row) * 256 + k0) << 1) + (c << 4);
            *(float4*)((char*)Bs + dstoff) = *(const float4*)pb;
        }
        __syncthreads();
#pragma unroll
        for (int kk = 0; kk < 2; kk++) {
            int ck = kk * 4 + lk;
            bf16x8 af[4], bg[4];
#pragma unroll
            for (int t = 0; t < 4; t++) {
                int ra = wm + t * 16 + lrow;
                af[t] = *(const bf16x8*)((const char*)As + ra * 128 + ((ck ^ (ra & 7)) << 4));
                int rb = wn + t * 16 + lrow;
                bg[t] = *(const bf16x8*)((const char*)Bs + rb * 128 + ((ck ^ (rb & 7)) << 4));
            }
#pragma unroll
            for (int i2 = 0; i2 < 4; i2++)
#pragma unroll
                for (int j2 = 0; j2 < 4; j2++)
                    acc[i2][j2] = __builtin_amdgcn_mfma_f32_16x16x32_bf16(
                        af[i2], bg[j2], acc[i2][j2], 0, 0, 0);
        }
        __syncthreads();
    }
#pragma unroll
    for (int i2 = 0; i2 < 4; i2++) {
#pragma unroll
        for (int j2 = 0; j2 < 4; j2++) {
            int col = n0 + wn + j2 * 16 + lrow;
            int rowb = m0 + wm + i2 * 16 + lk * 4;
#pragma unroll
            for (int rg = 0; rg < 4; rg++)
                S[(size_t)(rowb + rg) * NN + col] = acc[i2][j2][rg];
        }
    }
}

// ---------------------------------------------------------------- BatchNorm
__global__ void bn_stats(const float* __restrict__ Y, float* __restrict__ csum,
                         float* __restrict__ csum2) {
    int t = threadIdx.x;
    float s0 = 0.f, s1 = 0.f, s2v = 0.f;
    float q0 = 0.f, q1 = 0.f, q2 = 0.f;
    int r0 = blockIdx.x * 16;
    for (int i = r0; i < r0 + 16; i++) {
        const float* row = Y + (size_t)i * FEAT;
        float a = row[t], b = row[t + 256], c = row[t + 512];
        s0 += a; q0 += a * a;
        s1 += b; q1 += b * b;
        s2v += c; q2 += c * c;
    }
    atomicAdd(&csum[t], s0);        atomicAdd(&csum2[t], q0);
    atomicAdd(&csum[t + 256], s1);  atomicAdd(&csum2[t + 256], q1);
    atomicAdd(&csum[t + 512], s2v); atomicAdd(&csum2[t + 512], q2);
}

// bn_norm2: derives scale/shift per block; writes fp32 + bf16
__global__ void bn_norm2(float* __restrict__ Y,
                         const float* __restrict__ csum, const float* __restrict__ csum2,
                         const float* __restrict__ g0, const float* __restrict__ g1,
                         const float* __restrict__ g2, const float* __restrict__ b0,
                         const float* __restrict__ b1, const float* __restrict__ b2,
                         short* __restrict__ Yc) {
    __shared__ float sc[FEAT], sh[FEAT];
    for (int jx = threadIdx.x; jx < FEAT; jx += 256) {
        float mean = csum[jx] * (1.f / NN);
        float var = fmaxf(csum2[jx] * (1.f / NN) - mean * mean, 0.f);
        int m = jx >> 8, jj = jx & 255;
        const float* g = (m == 0) ? g0 : (m == 1) ? g1 : g2;
        const float* bt = (m == 0) ? b0 : (m == 1) ? b1 : b2;
        float s = g[jj] / sqrtf(var + 1e-5f);
        sc[jx] = s;
        sh[jx] = bt[jj] - mean * s;
    }
    __syncthreads();
    const int n4 = NN * FEAT / 4;
    for (int i = blockIdx.x * 256 + threadIdx.x; i < n4; i += gridDim.x * 256) {
        float4 v = *(const float4*)(Y + (size_t)i * 4);
        int m = i / 192;
        int c = (i - m * 192) * 4;
        v.x = v.x * sc[c + 0] + sh[c + 0];
        v.y = v.y * sc[c + 1] + sh[c + 1];
        v.z = v.z * sc[c + 2] + sh[c + 2];
        v.w = v.w * sc[c + 3] + sh[c + 3];
        *(float4*)(Y + (size_t)i * 4) = v;
        *(short4*)(Yc + (size_t)m * FEAT + c) =
            make_short4((short)f2bf(v.x), (short)f2bf(v.y), (short)f2bf(v.z), (short)f2bf(v.w));
    }
}

// ---------------------------------------------------------------- row normalize z -> bf16 Zc
__global__ void rownorm_kernel(const float* __restrict__ Zin, short* __restrict__ Zc) {
    int i = blockIdx.x;
    int c = threadIdx.x;
    __shared__ float rs[256];
    __shared__ float inv;
    float v = Zin[(size_t)i * HIDD + c];
    rs[c] = v * v;
    __syncthreads();
    for (int st = 128; st > 0; st >>= 1) {
        if (c < st) rs[c] += rs[c + st];
        __syncthreads();
    }
    if (c == 0) inv = 1.f / (sqrtf(rs[0]) + 1e-8f);
    __syncthreads();
    Zc[(size_t)i * 256 + c] = (short)f2bf(v * inv);
}

// ---------------------------------------------------------------- top-k via radix select (1 block/row)
__global__ __launch_bounds__(256) void topk_hist(const float* __restrict__ S,
        float* __restrict__ hv, int* __restrict__ eidx,
        float* __restrict__ De, float* __restrict__ ew,
        float* __restrict__ Dv, float* __restrict__ Dv2, int* __restrict__ row_cnt) {
    int row = blockIdx.x, tid = threadIdx.x, wave = tid >> 6;
    __shared__ unsigned hist[4][256];
    __shared__ unsigned suf[256];
    __shared__ int sb, sAbove, scand;
    __shared__ unsigned ckey[128];
    __shared__ int ccol[128];
    __shared__ int ccnt;
    __shared__ float wsum;
    const float4* base = (const float4*)(S + (size_t)row * NN);
    unsigned key[12];
#pragma unroll
    for (int c = 0; c < 3; c++) {
        float4 q = base[tid + c * 256];
        unsigned u0 = __float_as_uint(q.x), u1 = __float_as_uint(q.y);
        unsigned u2 = __float_as_uint(q.z), u3 = __float_as_uint(q.w);
        key[c * 4 + 0] = u0 ^ ((((int)u0) >> 31) | 0x80000000u);
        key[c * 4 + 1] = u1 ^ ((((int)u1) >> 31) | 0x80000000u);
        key[c * 4 + 2] = u2 ^ ((((int)u2) >> 31) | 0x80000000u);
        key[c * 4 + 3] = u3 ^ ((((int)u3) >> 31) | 0x80000000u);
    }
    if (tid == 0) { ccnt = 0; wsum = 0.f; }
    unsigned prefix = 0;
    int cAbove = 0, shift = 24;
    for (int level = 0; level < 4; level++) {
        shift = 24 - 8 * level;
#pragma unroll
        for (int w2 = 0; w2 < 4; w2++) hist[w2][tid] = 0;
        __syncthreads();
#pragma unroll
        for (int i = 0; i < 12; i++) {
            bool in = (level == 0) || ((key[i] >> (shift + 8)) == prefix);
            if (in) atomicAdd(&hist[wave][(key[i] >> shift) & 255], 1u);
        }
        __syncthreads();
        suf[tid] = hist[0][tid] + hist[1][tid] + hist[2][tid] + hist[3][tid];
        __syncthreads();
        for (int s2 = 1; s2 < 256; s2 <<= 1) {
            unsigned a = (tid + s2 < 256) ? suf[tid + s2] : 0u;
            __syncthreads();
            suf[tid] += a;
            __syncthreads();
        }
        int need = 16 - cAbove;
        unsigned nxt = (tid < 255) ? suf[tid + 1] : 0u;
        if ((int)suf[tid] >= need && (tid == 255 || (int)nxt < need)) {
            sb = tid;
            sAbove = cAbove + (int)nxt;
            scand = cAbove + (int)suf[tid];
        }
        __syncthreads();
        prefix = (prefix << 8) | (unsigned)sb;
        cAbove = sAbove;
        if (scand <= 112 || shift == 0) break;
        __syncthreads();
    }
    __syncthreads();
#pragma unroll
    for (int i = 0; i < 12; i++) {
        if ((key[i] >> shift) >= prefix) {
            int idx = atomicAdd(&ccnt, 1);
            if (idx < 128) {
                ckey[idx] = key[i];
                ccol[idx] = tid * 4 + ((i >> 2) << 10) + (i & 3);
            }
        }
    }
    __syncthreads();
    int n = min(ccnt, 128);
    float w = 0.f;
    int mycol = 0, myrank = 1 << 30;
    if (tid < n) {
        unsigned ki = ckey[tid];
        int ci = ccol[tid];
        int rank = 0;
        for (int jx = 0; jx < n; jx++) {
            unsigned kj = ckey[jx];
            int cj = ccol[jx];
            rank += (kj > ki) || (kj == ki && cj < ci);
        }
        if (rank < TK) {
            unsigned u = (ki & 0x80000000u) ? (ki ^ 0x80000000u) : ~ki;
            float val = __uint_as_float(u);
            float sg = 1.f / (1.f + expf(-val));
            w = (sg > 0.5f) ? sg : 0.f;
            hv[row * TK + rank] = w;
            eidx[row * TK + rank] = ci;
            myrank = rank; mycol = ci;
            atomicAdd(&wsum, w);
        }
    }
    __syncthreads();
    float s = wsum;
    if (tid == 0) { De[row] = s + 1e-8f; ew[row] = s * (1.f / TK); }
    float ewv = s * (1.f / TK);
    if (myrank < TK) {
        atomicAdd(&Dv[mycol], w * ewv);
        atomicAdd(&Dv2[mycol], w);
        atomicAdd(&row_cnt[mycol], 1);
    }
}

// ---------------------------------------------------------------- CSR scan + degree finalize
__global__ void scan_deg(const int* __restrict__ cnt, int* __restrict__ start,
                         const float* __restrict__ Dv, float* __restrict__ Dv2,
                         float* __restrict__ dvis) {
    __shared__ int part[256];
    int t = threadIdx.x;
    const int chunk = NN / 256;
    int s = 0;
    for (int i = t * chunk; i < (t + 1) * chunk; i++) {
        s += cnt[i];
        dvis[i] = 1.f / sqrtf(Dv[i] + 1e-8f);
        Dv2[i] += 1e-8f;
    }
    part[t] = s;
    __syncthreads();
    if (t == 0) {
        int a = 0;
        for (int i = 0; i < 256; i++) { int v = part[i]; part[i] = a; a += v; }
    }
    __syncthreads();
    int a = part[t];
    for (int i = t * chunk; i < (t + 1) * chunk; i++) { start[i] = a; a += cnt[i]; }
    if (t == 255) start[NN] = a;
}

__global__ void fill_csr(const int* __restrict__ eidx, const float* __restrict__ hv,
                         const int* __restrict__ start, int* __restrict__ fillc,
                         int* __restrict__ csr_e, float* __restrict__ csr_w) {
    int t = blockIdx.x * 256 + threadIdx.x;
    if (t >= NN * TK) return;
    int e = t >> 4;
    int v = eidx[t];
    int pos = atomicAdd(&fillc[v], 1);
    int pp = start[v] + pos;
    csr_e[pp] = e;
    csr_w[pp] = hv[t];
}

// ---------------------------------------------------------------- sparse H ops
__global__ void edge_gather4(const int* __restrict__ eidx, const float* __restrict__ hv,
                             const float* __restrict__ De, const float* __restrict__ dvis,
                             const float* __restrict__ X, float* __restrict__ T,
                             int F4, int ldx4, int ldt4, int epb, int use_dvis) {
    int slot = threadIdx.x / F4;
    if (slot >= epb) return;
    int f = threadIdx.x - slot * F4;
    int e = blockIdx.x * epb + slot;
    const int* ei = eidx + e * TK;
    const float* hw = hv + e * TK;
    float ax = 0.f, ay = 0.f, az = 0.f, aw = 0.f;
#pragma unroll
    for (int jx = 0; jx < TK; jx++) {
        int v = ei[jx];
        float w = hw[jx];
        if (use_dvis) w *= dvis[v];
        const float4 x = *(const float4*)(X + ((size_t)v * ldx4 + f) * 4);
        ax = fmaf(w, x.x, ax); ay = fmaf(w, x.y, ay);
        az = fmaf(w, x.z, az); aw = fmaf(w, x.w, aw);
    }
    float inv = 1.f / De[e];
    *(float4*)(T + ((size_t)e * ldt4 + f) * 4) = make_float4(ax * inv, ay * inv, az * inv, aw * inv);
}

__global__ void row_gather4(const int* __restrict__ start, const int* __restrict__ csr_e,
                            const float* __restrict__ csr_w, const float* __restrict__ dvis,
                            const float* __restrict__ T, float* __restrict__ Y,
                            int F4, int ldt4, int ldy4, int epb, int use_dvis) {
    int slot = threadIdx.x / F4;
    if (slot >= epb) return;
    int f = threadIdx.x - slot * F4;
    int v = blockIdx.x * epb + slot;
    int s0 = start[v], s1 = start[v + 1];
    float ax = 0.f, ay = 0.f, az = 0.f, aw = 0.f;
    for (int p = s0; p < s1; p++) {
        float w = csr_w[p];
        const float4 x = *(const float4*)(T + ((size_t)csr_e[p] * ldt4 + f) * 4);
        ax = fmaf(w, x.x, ax); ay = fmaf(w, x.y, ay);
        az = fmaf(w, x.z, az); aw = fmaf(w, x.w, aw);
    }
    float sc = use_dvis ? dvis[v] : 1.f;
    *(float4*)(Y + ((size_t)v * ldy4 + f) * 4) =
        make_float4(ax * sc, ay * sc, az * sc, aw * sc);
}

// spectral: row_gather fused with Rayleigh sums
__global__ void rg_spec(const int* __restrict__ start, const int* __restrict__ csr_e,
                        const float* __restrict__ csr_w, const float* __restrict__ T,
                        const float* __restrict__ r, const float* __restrict__ Dv2,
                        float* __restrict__ numb, float* __restrict__ denb) {
    __shared__ float lsn[64], lsd[64];
    int tid = threadIdx.x;
    if (tid < 64) { lsn[tid] = 0.f; lsd[tid] = 0.f; }
    __syncthreads();
    int slot = tid >> 4, f = tid & 15;
    int v = blockIdx.x * 16 + slot;
    int s0 = start[v], s1 = start[v + 1];
    float ax = 0.f, ay = 0.f, az = 0.f, aw = 0.f;
    for (int p = s0; p < s1; p++) {
        float w = csr_w[p];
        const float4 x = *(const float4*)(T + ((size_t)csr_e[p] * 16 + f) * 4);
        ax = fmaf(w, x.x, ax); ay = fmaf(w, x.y, ay);
        az = fmaf(w, x.z, az); aw = fmaf(w, x.w, aw);
    }
    float d2 = Dv2[v];
    const float4 rv = *(const float4*)(r + (size_t)v * 64 + f * 4);
    atomicAdd(&lsn[f * 4 + 0], rv.x * (d2 * rv.x - ax));
    atomicAdd(&lsn[f * 4 + 1], rv.y * (d2 * rv.y - ay));
    atomicAdd(&lsn[f * 4 + 2], rv.z * (d2 * rv.z - az));
    atomicAdd(&lsn[f * 4 + 3], rv.w * (d2 * rv.w - aw));
    atomicAdd(&lsd[f * 4 + 0], d2 * rv.x * rv.x);
    atomicAdd(&lsd[f * 4 + 1], d2 * rv.y * rv.y);
    atomicAdd(&lsd[f * 4 + 2], d2 * rv.z * rv.z);
    atomicAdd(&lsd[f * 4 + 3], d2 * rv.w * rv.w);
    __syncthreads();
    if (tid < 64) {
        atomicAdd(&numb[tid], lsn[tid]);
        atomicAdd(&denb[tid], lsd[tid]);
    }
}

// ---------------------------------------------------------------- cheb combine (bf16 out)
__global__ void cheb_combine(const float* __restrict__ A0, int ld0,
                             const float* __restrict__ A1, int ld1,
                             const float* __restrict__ A2, int ld2,
                             const float* __restrict__ A3, int ld3,
                             const float* __restrict__ bias, float e1, float e2,
                             float* __restrict__ Xf, int ldf, short* __restrict__ Xc,
                             int Fw, int total4) {
    int i = blockIdx.x * 256 + threadIdx.x;
    if (i >= total4) return;
    int F4 = Fw >> 2;
    int m = i / F4, n4 = i - m * F4;
    float4 g0 = *(const float4*)(A0 + ((size_t)m * ld0 + n4) * 4);
    float4 g1 = *(const float4*)(A1 + ((size_t)m * ld1 + n4) * 4);
    float4 g2 = *(const float4*)(A2 + ((size_t)m * ld2 + n4) * 4);
    float4 g3 = *(const float4*)(A3 + ((size_t)m * ld3 + n4) * 4);
    float4 b = *(const float4*)(bias + n4 * 4);
    float4 x;
    x.x = fmaxf(g0.x - e1 * g1.x - e2 * g2.x + 2.f * e2 * g3.x + b.x, 0.f);
    x.y = fmaxf(g0.y - e1 * g1.y - e2 * g2.y + 2.f * e2 * g3.y + b.y, 0.f);
    x.z = fmaxf(g0.z - e1 * g1.z - e2 * g2.z + 2.f * e2 * g3.z + b.z, 0.f);
    x.w = fmaxf(g0.w - e1 * g1.w - e2 * g2.w + 2.f * e2 * g3.w + b.w, 0.f);
    if (Xf) *(float4*)(Xf + ((size_t)m * ldf + n4) * 4) = x;
    if (Xc)
        *(short4*)(Xc + (size_t)m * Fw + n4 * 4) =
            make_short4((short)f2bf(x.x), (short)f2bf(x.y), (short)f2bf(x.z), (short)f2bf(x.w));
}

// ---------------------------------------------------------------- fused heads: r + scores
__global__ __launch_bounds__(256) void heads_fused(const float* __restrict__ x2,
        const float* __restrict__ rw1, const float* __restrict__ rb1,
        const float* __restrict__ rw2, const float* __restrict__ rb2,
        const float* __restrict__ aw1, const float* __restrict__ ab1,
        const float* __restrict__ aw2, const float* __restrict__ ab2,
        float* __restrict__ r, float* __restrict__ out) {
    __shared__ float w1[128 * 64];
    __shared__ float w2[64 * 64];
    __shared__ float a1[64 * 32];
    __shared__ float a2s[32];
    __shared__ float xr[4][128];
    int tid = threadIdx.x;
    for (int i = tid; i < 128 * 64 / 4; i += 256)
        *(float4*)&w1[i * 4] = *(const float4*)&rw1[i * 4];
    for (int i = tid; i < 64 * 64 / 4; i += 256)
        *(float4*)&w2[i * 4] = *(const float4*)&rw2[i * 4];
    for (int i = tid; i < 64 * 32 / 4; i += 256)
        *(float4*)&a1[i * 4] = *(const float4*)&aw1[i * 4];
    if (tid < 32) a2s[tid] = aw2[tid];
    __syncthreads();
    int wave = tid >> 6, lane = tid & 63;
    float ab2v = ab2[0];
    for (int rr = 0; rr < 4; rr++) {
        int row = blockIdx.x * 16 + rr * 4 + wave;
        *(float2*)&xr[wave][lane * 2] = *(const float2*)&x2[(size_t)row * 128 + lane * 2];
        float hacc = rb1[lane];
#pragma unroll 8
        for (int k = 0; k < 128; k++) hacc = fmaf(xr[wave][k], w1[k * 64 + lane], hacc);
        hacc = fmaxf(hacc, 0.f);
        xr[wave][lane] = hacc;
        float racc = rb2[lane];
#pragma unroll 8
        for (int k = 0; k < 64; k++) racc = fmaf(xr[wave][k], w2[k * 64 + lane], racc);
        r[(size_t)row * 64 + lane] = racc;
        xr[wave][lane] = racc;
        int g = lane >> 5, jx = lane & 31;
        float hp = 0.f;
#pragma unroll 8
        for (int k = 0; k < 32; k++) hp = fmaf(xr[wave][g * 32 + k], a1[(g * 32 + k) * 32 + jx], hp);
        hp += __shfl_xor(hp, 32);
        float hj = fmaxf(hp + ab1[jx], 0.f) * a2s[jx];
#pragma unroll
        for (int s2 = 1; s2 < 32; s2 <<= 1) hj += __shfl_xor(hj, s2);
        if (lane == 0) out[row] = 1.f / (1.f + expf(-(hj + ab2v)));
    }
}

__global__ void finals_kernel(const float* __restrict__ msum, const float* __restrict__ numb,
                              const float* __restrict__ denb, float* __restrict__ out) {
    if (threadIdx.x == 0 && blockIdx.x == 0) {
        float s = 0.f;
        for (int c = 0; c < 64; c++) s += numb[c] / (denb[c] + 1e-8f);
        out[NN + 1] = s * (1.f / 64.f);
        out[NN] = msum[0] * (1.f / ((float)NN * FEAT));
    }
}

// ================================================================ launch
extern "C" void kernel_launch(void* const* d_in, const int* in_sizes, int n_in,
                              void* d_out, int out_size, void* d_ws, size_t ws_size,
                              hipStream_t stream) {
    const float* images = (const float*)d_in[0];
    const float* text   = (const float*)d_in[1];
    const float* signal = (const float*)d_in[2];
    const float* iw1 = (const float*)d_in[3];  const float* ib1 = (const float*)d_in[4];
    const float* iw2 = (const float*)d_in[5];  const float* ib2 = (const float*)d_in[6];
    const float* ig  = (const float*)d_in[7];  const float* ibeta = (const float*)d_in[8];
    const float* tw1 = (const float*)d_in[9];  const float* tb1 = (const float*)d_in[10];
    const float* tw2 = (const float*)d_in[11]; const float* tb2 = (const float*)d_in[12];
    const float* tg  = (const float*)d_in[13]; const float* tbeta = (const float*)d_in[14];
    const float* sw1 = (const float*)d_in[15]; const float* sb1 = (const float*)d_in[16];
    const float* sw2 = (const float*)d_in[17]; const float* sb2 = (const float*)d_in[18];
    const float* sg  = (const float*)d_in[19]; const float* sbeta = (const float*)d_in[20];
    const float* gw  = (const float*)d_in[21]; const float* gb = (const float*)d_in[22];
    const float* c1w = (const float*)d_in[23]; const float* c1b = (const float*)d_in[24];
    const float* c2w = (const float*)d_in[25]; const float* c2b = (const float*)d_in[26];
    const float* rw1 = (const float*)d_in[27]; const float* rb1 = (const float*)d_in[28];
    const float* rw2 = (const float*)d_in[29]; const float* rb2 = (const float*)d_in[30];
    const float* aw1 = (const float*)d_in[31]; const float* ab1 = (const float*)d_in[32];
    const float* aw2 = (const float*)d_in[33]; const float* ab2 = (const float*)d_in[34];
    const float* dw1 = (const float*)d_in[35]; const float* db1 = (const float*)d_in[36];
    const float* dw2 = (const float*)d_in[37]; const float* db2 = (const float*)d_in[38];
    float* out = (float*)d_out;

    float* wsf = (float*)d_ws;
    size_t off = 0;
    auto AF = [&](size_t n) { float* q = wsf + off; off += n; return q; };
    float* feats  = AF((size_t)NN * FEAT);
    float* simbuf = AF((size_t)NN * NN);
    float* p      = AF((size_t)NN * 192);
    float* z      = AF((size_t)NN * HIDD);
    float* x2     = AF((size_t)NN * 128);
    float* r      = AF((size_t)NN * 64);
    float* hv     = AF((size_t)NN * TK);
    float* ew     = AF(NN);
    float* De     = AF(NN);
    float* Dv     = AF(NN);
    float* Dv2    = AF(NN);
    float* dvis   = AF(NN);
    float* csr_w  = AF((size_t)NN * TK);
    float* numb   = AF(64);
    float* denb   = AF(64);
    float* msum   = AF(1);
    float* csum   = AF(FEAT);
    float* csum2  = AF(FEAT);
    short* x1c    = (short*)AF((size_t)NN * 128);     // [NN][256] bf16; reused as hc
    short* wcbuf  = (short*)AF(1589248);
    float* Gbuf   = AF((size_t)NN * FEAT);            // MLP1 partials, then G0|G1|G2 (ld 768)
    int* eidx     = (int*)(wsf + off); off += (size_t)NN * TK;
    int* csr_e    = (int*)(wsf + off); off += (size_t)NN * TK;
    int* row_cnt  = (int*)(wsf + off); off += NN;
    int* row_fill = (int*)(wsf + off); off += NN;
    int* row_start= (int*)(wsf + off); off += NN + 1;

    short* Zc = (short*)z;
    short* hc = x1c;   // reuse post-cheb2

    // weight bf16 sub-buffers
    short* wp = wcbuf;
    auto AW = [&](size_t n) { short* q = wp; wp += n; return q; };
    short* iw1c = AW((size_t)256 * 192);
    short* tw1c = AW((size_t)256 * 768);
    short* sw1c = AW((size_t)256 * 256);
    short* iw2c = AW((size_t)256 * 256);
    short* tw2c = AW((size_t)256 * 256);
    short* sw2c = AW((size_t)256 * 256);
    short* gwc  = AW((size_t)256 * 768);
    short* c1wc0 = AW((size_t)256 * 768);
    short* c1wc1 = AW((size_t)256 * 768);
    short* c1wc2 = AW((size_t)256 * 768);
    short* c2wc0 = AW((size_t)128 * 256);
    short* c2wc1 = AW((size_t)128 * 256);
    short* c2wc2 = AW((size_t)128 * 256);
    short* dw2c  = AW((size_t)768 * 256);

    // pre-sim simbuf layout (shorts)
    short* sbp = (short*)simbuf;
    short* pc  = sbp;
    short* tc  = pc + (size_t)NN * 192;
    short* scb = tc + (size_t)NN * 768;
    short* hc0 = scb + (size_t)NN * 256;
    short* hc1 = hc0 + (size_t)NN * 256;
    short* hc2 = hc1 + (size_t)NN * 256;
    short* featsc_pre = hc2 + (size_t)NN * 256;

    // post-topk slabs (floats)
    float* et1   = simbuf;                              // NN*512
    float* MG12  = simbuf + (size_t)NN * 512;           // NN*512
    float* et2   = simbuf + (size_t)NN * 1024;          // NN*256
    float* MMG2  = simbuf + (size_t)NN * 1280;          // NN*256
    float* Hb    = simbuf;                              // NN*384 (cheb2)
    float* et3   = simbuf + (size_t)NN * 384;
    float* MH12  = simbuf + (size_t)NN * 640;
    float* et4   = simbuf + (size_t)NN * 896;
    float* MMH2  = simbuf + (size_t)NN * 1024;
    float* et5   = simbuf + (size_t)NN * 2048;

    dim3 blk(256);
    auto eg = [&](const float* X, int ldx4, float* T, int ldt4, int F, int use_dvis) {
        int F4 = F / 4, epb = 256 / F4 < 1 ? 1 : 256 / F4;
        edge_gather4<<<NN / epb, dim3(F4 * epb), 0, stream>>>(
            eidx, hv, De, dvis, X, T, F4, ldx4, ldt4, epb, use_dvis);
    };
    auto rg = [&](const float* T, int ldt4, float* Y, int ldy4, int F, int use_dvis) {
        int F4 = F / 4, epb = 256 / F4 < 1 ? 1 : 256 / F4;
        row_gather4<<<NN / epb, dim3(F4 * epb), 0, stream>>>(
            row_start, csr_e, csr_w, dvis, T, Y, F4, ldt4, ldy4, epb, use_dvis);
    };
    auto mkbj = [](const short* A, const short* B, const float* bias, float* Cf, short* Cc,
                   const float* mref, int sa, int sb, int Koff, int Klen, int act,
                   int ldc, int ccW, int pslot) {
        BJ j{};
        j.A = A; j.Bw = B; j.bias = bias; j.Cf = Cf; j.Cc = Cc; j.mseRef = mref;
        j.sa = sa; j.sb = sb; j.Koff = Koff; j.Klen = Klen; j.act = act;
        j.ldc = ldc; j.ccW = ccW; j.pslot = pslot; j.scale = 1.f;
        return j;
    };

    const float E1 = 0.60653065971f;  // exp(-0.5)
    const float E2 = 0.36787944117f;  // exp(-1.0)

    // ---- pool + zero-init + conversions ----
    pool_kernel<<<(NN * 192 + 255) / 256, blk, 0, stream>>>(
        images, p, Dv, Dv2, row_cnt, row_fill, csum, numb, msum);
    {
        WJobs wj{};
        wj.j[0] = {iw1, iw1c, 192, 256};
        wj.j[1] = {tw1, tw1c, 768, 256};
        wj.j[2] = {sw1, sw1c, 256, 256};
        wj.j[3] = {iw2, iw2c, 256, 256};
        wj.j[4] = {tw2, tw2c, 256, 256};
        wj.j[5] = {sw2, sw2c, 256, 256};
        wj.j[6] = {gw,  gwc,  768, 256};
        wj.j[7] = {c1w, c1wc0, 768, 256};
        wj.j[8] = {c1w + (size_t)FEAT * HIDD, c1wc1, 768, 256};
        wj.j[9] = {c1w + (size_t)2 * FEAT * HIDD, c1wc2, 768, 256};
        wj.j[10] = {c2w, c2wc0, 256, 128};
        wj.j[11] = {c2w + (size_t)HIDD * 128, c2wc1, 256, 128};
        wj.j[12] = {c2w + (size_t)2 * HIDD * 128, c2wc2, 256, 128};
        wj.j[13] = {dw2, dw2c, 256, 768};
        wsplitT<<<dim3(24, 24, 14), blk, 0, stream>>>(wj);
    }
    split_rows3<<<(NN * 304 + 255) / 256, blk, 0, stream>>>(p, pc, text, tc, signal, scb);

    // ---- MLP1: 5 balanced jobs (text K split into 3 partials) ----
    {
        BTJ bt{};
        bt.j[0] = mkbj(pc, iw1c, ib1, nullptr, hc0, nullptr, 192, 192, 0, 192, 1, 0, 256, -1);
        bt.j[1] = mkbj(tc, tw1c, nullptr, nullptr, nullptr, nullptr, 768, 768, 0, 256, 0, 0, 0, 0);
        bt.j[2] = mkbj(tc, tw1c, nullptr, nullptr, nullptr, nullptr, 768, 768, 256, 256, 0, 0, 0, 1);
        bt.j[3] = mkbj(tc, tw1c, nullptr, nullptr, nullptr, nullptr, 768, 768, 512, 256, 0, 0, 0, 2);
        bt.j[4] = mkbj(scb, sw1c, sb1, nullptr, hc2, nullptr, 256, 256, 0, 256, 1, 0, 256, -1);
        gemm_btj<<<dim3(4, 24, 5), blk, 0, stream>>>(bt, Gbuf, nullptr, NN, 256);
        epi3<<<(NN * 256 + 255) / 256, blk, 0, stream>>>(Gbuf, tb1, hc1, NN, 256, 256);
    }
    // ---- MLP2: 3 jobs ----
    {
        BTJ bt{};
        bt.j[0] = mkbj(hc0, iw2c, ib2, feats, nullptr, nullptr, 256, 256, 0, 256, 0, FEAT, 0, -1);
        bt.j[1] = mkbj(hc1, tw2c, tb2, feats + 256, nullptr, nullptr, 256, 256, 0, 256, 0, FEAT, 0, -1);
        bt.j[2] = mkbj(hc2, sw2c, sb2, feats + 512, nullptr, nullptr, 256, 256, 0, 256, 0, FEAT, 0, -1);
        gemm_btj<<<dim3(4, 24, 3), blk, 0, stream>>>(bt, nullptr, nullptr, NN, 256);
    }
    bn_stats<<<NN / 16, blk, 0, stream>>>(feats, csum, csum2);
    bn_norm2<<<1024, blk, 0, stream>>>(feats, csum, csum2, ig, tg, sg, ibeta, tbeta, sbeta, featsc_pre);

    // ---- gw + cheb1-G merged (4 jobs, all K=768, shared A) ----
    {
        BTJ bt{};
        bt.j[0] = mkbj(featsc_pre, gwc, gb, z, nullptr, nullptr, 768, 768, 0, 768, 2, 256, 0, -1);
        bt.j[1] = mkbj(featsc_pre, c1wc0, nullptr, Gbuf, nullptr, nullptr, 768, 768, 0, 768, 0, 768, 0, -1);
        bt.j[2] = mkbj(featsc_pre, c1wc1, nullptr, Gbuf + 256, nullptr, nullptr, 768, 768, 0, 768, 0, 768, 0, -1);
        bt.j[3] = mkbj(featsc_pre, c1wc2, nullptr, Gbuf + 512, nullptr, nullptr, 768, 768, 0, 768, 0, 768, 0, -1);
        gemm_btj<<<dim3(4, 24, 4), blk, 0, stream>>>(bt, nullptr, nullptr, NN, 256);
    }
    rownorm_kernel<<<NN, blk, 0, stream>>>(z, Zc);
    sim_mfma<<<dim3(NN / 128, NN / 128), blk, 0, stream>>>(Zc, simbuf);
    topk_hist<<<NN, blk, 0, stream>>>(simbuf, hv, eidx, De, ew, Dv, Dv2, row_cnt);

    // ---- CSR ----
    scan_deg<<<1, blk, 0, stream>>>(row_cnt, row_start, Dv, Dv2, dvis);
    fill_csr<<<NN * TK / 256, blk, 0, stream>>>(eidx, hv, row_start, row_fill, csr_e, csr_w);

    // ---- cheb conv 1 ----
    eg(Gbuf + 256, 192, et1, 128, 512, 1);
    rg(et1, 128, MG12, 128, 512, 1);
    eg(MG12 + 256, 128, et2, 64, 256, 1);
    rg(et2, 64, MMG2, 64, 256, 1);
    cheb_combine<<<(NN * 64 + 255) / 256, blk, 0, stream>>>(
        Gbuf, 192, MG12, 128, Gbuf + 512, 192, MMG2, 64,
        c1b, E1, E2, nullptr, 0, x1c, 256, NN * 64);

    // ---- cheb conv 2 ----
    {
        BTJ bt{};
        bt.j[0] = mkbj(x1c, c2wc0, nullptr, Hb, nullptr, nullptr, 256, 256, 0, 256, 0, 384, 0, -1);
        bt.j[1] = mkbj(x1c, c2wc1, nullptr, Hb + 128, nullptr, nullptr, 256, 256, 0, 256, 0, 384, 0, -1);
        bt.j[2] = mkbj(x1c, c2wc2, nullptr, Hb + 256, nullptr, nullptr, 256, 256, 0, 256, 0, 384, 0, -1);
        gemm_btj<<<dim3(2, 24, 3), blk, 0, stream>>>(bt, nullptr, nullptr, NN, 128);
    }
    eg(Hb + 128, 96, et3, 64, 256, 1);
    rg(et3, 64, MH12, 64, 256, 1);
    eg(MH12 + 128, 64, et4, 32, 128, 1);
    rg(et4, 32, MMH2, 32, 128, 1);
    cheb_combine<<<(NN * 32 + 255) / 256, blk, 0, stream>>>(
        Hb, 96, MH12, 64, Hb + 256, 96, MMH2, 32,
        c2b, E1, E2, x2, 32, nullptr, 128, NN * 32);

    // ---- heads ----
    heads_fused<<<NN / 16, blk, 0, stream>>>(x2, rw1, rb1, rw2, rb2,
                                             aw1, ab1, aw2, ab2, r, out);
    gemm_mf<<<dim3(4, 24), blk, 0, stream>>>(r, dw1, db1, hc, NN, 256, 64, 64, 256, 256);
    {
        BTJ bt{};
        bt.j[0] = mkbj(hc, dw2c, db2, nullptr, nullptr, feats, 256, 256, 0, 256, 0, 0, 0, -1);
        gemm_btj<<<dim3(12, 24, 1), blk, 0, stream>>>(bt, nullptr, msum, NN, 768);
    }

    // ---- spectral cut (fused) ----
    eg(r, 16, et5, 16, 64, 0);
    rg_spec<<<NN / 16, blk, 0, stream>>>(row_start, csr_e, csr_w, et5, r, Dv2, numb, denb);
    finals_kernel<<<1, 64, 0, stream>>>(msum, numb, denb, out);
}